// Round 12
// baseline (1495.270 us; speedup 1.0000x reference)
//
#include <hip/hip_runtime.h>
#include <math.h>

typedef unsigned short u16;
typedef _Float16 f16;
typedef f16 v8h __attribute__((ext_vector_type(8)));
typedef float v4f __attribute__((ext_vector_type(4)));
typedef unsigned v4u __attribute__((ext_vector_type(4)));

union Frag { v8h h; u16 s[8]; unsigned u[4]; v4u u4; };
union HU { f16 h; u16 u; };

// Scaled f16 pair split: v*64 ~= hi + lo * 2^-11, residual ~2^-22|v*64|.
__device__ __forceinline__ void fsplit16s(float v, u16& hi, u16& lo) {
    HU a, b;
    float vs = v * 64.f;                // exact (pow2 scale)
    a.h = (f16)vs;                      // RNE, rel err <= 2^-11
    float d = vs - (float)a.h;          // exact (Sterbenz)
    b.h = (f16)(d * 2048.f);            // rel err <= 2^-11 => total ~2^-22
    hi = a.u; lo = b.u;
}

// Same split, taken directly from a double (h publish path).
__device__ __forceinline__ void fsplit16d(double v, u16& hi, u16& lo) {
    HU a, b;
    double vs = v * 64.0;
    a.h = (f16)vs;                      // double->f16 RNE
    float d = (float)(vs - (double)a.h);
    b.h = (f16)(d * 2048.f);
    hi = a.u; lo = b.u;
}

__device__ __forceinline__ void split8s(const float* __restrict__ p, v8h& hi, v8h& lo) {
    Frag h, l;
#pragma unroll
    for (int j = 0; j < 8; ++j) {
        u16 a, b;
        fsplit16s(p[j], a, b);
        h.s[j] = a;
        l.s[j] = b;
    }
    hi = h.h; lo = l.h;
}

// Coherent (L1/L2-bypassing) 16B vector load; caller must s_waitcnt vmcnt(0).
__device__ __forceinline__ Frag load16_sc(const u16* p) {
    v4u r;
    asm volatile("global_load_dwordx4 %0, %1, off sc0 sc1" : "=v"(r) : "v"(p) : "memory");
    Frag f; f.u4 = r;
    return f;
}

// Cached 16B vector load at a pinned issue point; caller must s_waitcnt vmcnt(0).
__device__ __forceinline__ Frag load16_nc(const u16* p) {
    v4u r;
    asm volatile("global_load_dwordx4 %0, %1, off" : "=v"(r) : "v"(p) : "memory");
    Frag f; f.u4 = r;
    return f;
}

// ---------------------------------------------------------------------------
__global__ void prep_h(const float* __restrict__ hid, u16* __restrict__ hhi, u16* __restrict__ hlo) {
    int i = blockIdx.x * 256 + threadIdx.x;  // 65536
    u16 h, l;
    fsplit16s(hid[i], h, l);
    hhi[i] = h;
    hlo[i] = l;
}

// ---------------------------------------------------------------------------
// Transpose + scaled-f16-pair split (used for both U and W).
__global__ void transpose_split(const float* __restrict__ src, u16* __restrict__ dhi,
                                u16* __restrict__ dlo, int R, int C) {
    __shared__ float tile[32][33];
    int tid = threadIdx.x;
    int tx = tid & 31, ty = tid >> 5;
    int c0 = blockIdx.x * 32, r0 = blockIdx.y * 32;
#pragma unroll
    for (int i = 0; i < 4; ++i)
        tile[ty + i * 8][tx] = src[(size_t)(r0 + ty + i * 8) * C + c0 + tx];
    __syncthreads();
#pragma unroll
    for (int i = 0; i < 4; ++i) {
        int c = c0 + ty + i * 8;
        float v = tile[tx][ty + i * 8];
        size_t o = (size_t)c * R + r0 + tx;
        u16 h, l;
        fsplit16s(v, h, l);
        dhi[o] = h;
        dlo[o] = l;
    }
}

// ---------------------------------------------------------------------------
// xin = E[x] @ W + b0 -> f32 plane [8192][3072]
// ---------------------------------------------------------------------------
__global__ __launch_bounds__(256) void xin_kernel(
        const int* __restrict__ x, const float* __restrict__ E,
        const u16* __restrict__ WThi, const u16* __restrict__ WTlo,
        const float* __restrict__ b0, float* __restrict__ xin) {
    int tid = threadIdx.x;
    int wave = tid >> 6, lane = tid & 63;
    int n = lane & 15, q = lane >> 4;
    int wid = blockIdx.x * 4 + wave;   // 6144 waves
    int bt0 = (wid / 48) * 64;
    int j0 = (wid % 48) * 64;

    const float* arow[4];
#pragma unroll
    for (int mt = 0; mt < 4; ++mt)
        arow[mt] = E + (size_t)x[bt0 + mt * 16 + n] * 256 + q * 8;
    const u16* bhp[4];
    const u16* blp[4];
#pragma unroll
    for (int nt = 0; nt < 4; ++nt) {
        size_t r = (size_t)(j0 + nt * 16 + n) * 256 + q * 8;
        bhp[nt] = WThi + r;
        blp[nt] = WTlo + r;
    }

    v4f accH[4][4], accL[4][4];
#pragma unroll
    for (int mt = 0; mt < 4; ++mt)
#pragma unroll
        for (int nt = 0; nt < 4; ++nt) {
            accH[mt][nt] = (v4f){0.f, 0.f, 0.f, 0.f};
            accL[mt][nt] = (v4f){0.f, 0.f, 0.f, 0.f};
        }

    for (int kk = 0; kk < 8; ++kk) {
        v8h Bh[4], Bl[4];
#pragma unroll
        for (int nt = 0; nt < 4; ++nt) {
            Frag fh, fl;
            fh.u4 = *(const v4u*)(bhp[nt] + kk * 32);
            fl.u4 = *(const v4u*)(blp[nt] + kk * 32);
            Bh[nt] = fh.h;
            Bl[nt] = fl.h;
        }
#pragma unroll
        for (int mt = 0; mt < 4; ++mt) {
            v8h Ah, Al;
            split8s(arow[mt] + kk * 32, Ah, Al);
#pragma unroll
            for (int nt = 0; nt < 4; ++nt) {
                accH[mt][nt] = __builtin_amdgcn_mfma_f32_16x16x32_f16(Ah, Bh[nt], accH[mt][nt], 0, 0, 0);
                accL[mt][nt] = __builtin_amdgcn_mfma_f32_16x16x32_f16(Ah, Bl[nt], accL[mt][nt], 0, 0, 0);
                accL[mt][nt] = __builtin_amdgcn_mfma_f32_16x16x32_f16(Al, Bh[nt], accL[mt][nt], 0, 0, 0);
            }
        }
    }
    const double S12 = 2.44140625e-4;           // 2^-12
    const double S23 = 1.1920928955078125e-7;   // 2^-23
#pragma unroll
    for (int mt = 0; mt < 4; ++mt)
#pragma unroll
        for (int nt = 0; nt < 4; ++nt) {
            int j = j0 + nt * 16 + n;
            double bj = (double)b0[j];
#pragma unroll
            for (int r = 0; r < 4; ++r) {
                int bt = bt0 + mt * 16 + q * 4 + r;
                float v = (float)((double)accH[mt][nt][r] * S12 + (double)accL[mt][nt][r] * S23 + bj);
                __builtin_nontemporal_store(v, &xin[(size_t)bt * 3072 + j]);
            }
        }
}

__global__ void init_barrier(unsigned* __restrict__ bar) {
    bar[blockIdx.x * 256 + threadIdx.x] = 0u;  // 1024 subflags: 4 groups x 64 blocks x 4 waves
}

// ---------------------------------------------------------------------------
// Persistent GRU v16 = v13 (flag dataflow, 956us, absmax 4.9e-4) + XCD
// locality remap ONLY (isolated variable; v15 bundled it with staged gating
// which cost ~200us).  Remap: group bg=(bid&7)>>1 pinned to XCD pair
// {2bg,2bg+1} (hw round-robins bid%8 across XCDs), ut=((bid&1)<<5)|(bid>>3).
// v15's counters proved the remap makes the UTlo stream L2-resident
// (FETCH 244->109 MB): the 12 pre-gate Blo loads then hit L2 (~200cyc)
// instead of convoy-contended HBM (~900+cyc), and their latency hides under
// the flag poll rather than landing in the post-gate vmcnt(0) drain.
// Everything else byte-identical to v13.
// ---------------------------------------------------------------------------
__global__ __launch_bounds__(512, 1) void gru_persistent(
        const u16* __restrict__ UThi, const u16* __restrict__ UTlo,
        const float* __restrict__ b1, const float* __restrict__ xin,
        const float* __restrict__ hid,
        u16* __restrict__ hhi0, u16* __restrict__ hhi1,
        u16* __restrict__ hlo0, u16* __restrict__ hlo1,
        float* __restrict__ out, unsigned* __restrict__ bar) {
    // [3 gates][128 chunks][17 col-slots (16 used + pad)][8 elems]
    __shared__ u16 u_lds[3 * 128 * 17 * 8];   // 104448 B
    __shared__ float red[3][8][256];          // 24576 B
    int tid = threadIdx.x;
    int w = tid >> 6, lane = tid & 63;
    int n = lane & 15, q = lane >> 4;
    int bid = blockIdx.x;
    int bg = (bid & 7) >> 1;                   // XCD pair -> group
    int ut = ((bid & 1) << 5) | (bid >> 3);    // 0..63 within group (bijective)
    int b0r = bg * 16;
    int u0 = ut * 16;
    unsigned* sf = bar + bg * 256;               // group's 256 subflags
    unsigned* poll_addr = sf + w * 32 + (lane & 31);  // this wave's 32 producer subflags

    // --- Fill LDS with this block's U-hi slice (once) ---
    for (int i = tid; i < 3 * 128 * 16; i += 512) {  // 16B chunks
        int g = i >> 11;
        int rem = i & 2047;
        int chunk = rem >> 4;
        int col = rem & 15;
        *(v4u*)(u_lds + (size_t)((g * 128 + chunk) * 17 + col) * 8) =
            *(const v4u*)(UThi + (size_t)(g * 1024 + u0 + col) * 1024 + chunk * 8);
    }
    __syncthreads();

    size_t aoff = (size_t)(b0r + n) * 1024 + w * 128 + q * 8;
    size_t uloff = (size_t)(u0 + n) * 1024 + w * 128 + q * 8;

    // epilogue state (tid < 256)
    int bl = tid >> 4, ul = tid & 15;
    int bb = b0r + bl;
    int u = u0 + ul;
    size_t ho = (size_t)bb * 1024 + u;
    double bz = 0.0, br_ = 0.0, bh_ = 0.0, hp = 0.0;
    float xz = 0.f, xr = 0.f, xh = 0.f;
    if (tid < 256) {
        bz = (double)b1[u0 + ul];
        br_ = (double)b1[1024 + u0 + ul];
        bh_ = (double)b1[2048 + u0 + ul];
        hp = (double)hid[ho];
        size_t xo = (size_t)bb * 128 * 3072;
        xz = xin[xo + u];
        xr = xin[xo + 1024 + u];
        xh = xin[xo + 2048 + u];
    }

    const float S12 = 2.44140625e-4f;           // 2^-12 (exact pow2 scale)
    const float S23 = 1.1920928955078125e-7f;   // 2^-23

    for (int t = 0; t < 128; ++t) {
        const u16* hhi_in = (t & 1) ? hhi1 : hhi0;
        const u16* hlo_in = (t & 1) ? hlo1 : hlo0;
        u16* hhi_out = (t & 1) ? hhi0 : hhi1;
        u16* hlo_out = (t & 1) ? hlo0 : hlo1;

        // U-lo stream: issue before the poll so L2 latency hides under it.
        Frag Blo[3][4];
#pragma unroll
        for (int g = 0; g < 3; ++g)
#pragma unroll
            for (int kk = 0; kk < 4; ++kk)
                Blo[g][kk] = load16_nc(UTlo + uloff + (size_t)g * 1048576 + kk * 32);

        // --- Dataflow gate: wait for THIS wave's 8 producers (32 subflags).
        if (t > 0) {
            unsigned target = (unsigned)t;
            while (true) {
                unsigned v = __hip_atomic_load(poll_addr, __ATOMIC_RELAXED, __HIP_MEMORY_SCOPE_AGENT);
                if (__all(v >= target)) break;
                __builtin_amdgcn_s_sleep(1);
            }
        }

        // --- A fragments: coherent dwordx4 loads, all issued, one drain ---
        v8h Ah[4], Al[4];
#pragma unroll
        for (int kk = 0; kk < 4; ++kk) {
            Ah[kk] = load16_sc(hhi_in + aoff + kk * 32).h;
            Al[kk] = load16_sc(hlo_in + aoff + kk * 32).h;
        }
        asm volatile("s_waitcnt vmcnt(0)" ::: "memory");

        v4f az = {0.f, 0.f, 0.f, 0.f}, ag = az, ah = az;      // main (2^12 scale)
        v4f azl = az, agl = az, ahl = az;                      // aux (2^23 scale)
#pragma unroll
        for (int kk = 0; kk < 4; ++kk) {
            int chunk = w * 16 + kk * 4 + q;
            const u16* lp = u_lds + (size_t)(chunk * 17 + n) * 8;
            Frag f0, f1, f2;
            f0.u4 = *(const v4u*)(lp);
            f1.u4 = *(const v4u*)(lp + 128 * 17 * 8);
            f2.u4 = *(const v4u*)(lp + 2 * 128 * 17 * 8);
            v8h Bh0 = f0.h, Bh1 = f1.h, Bh2 = f2.h;
            az = __builtin_amdgcn_mfma_f32_16x16x32_f16(Ah[kk], Bh0, az, 0, 0, 0);
            ag = __builtin_amdgcn_mfma_f32_16x16x32_f16(Ah[kk], Bh1, ag, 0, 0, 0);
            ah = __builtin_amdgcn_mfma_f32_16x16x32_f16(Ah[kk], Bh2, ah, 0, 0, 0);
            azl = __builtin_amdgcn_mfma_f32_16x16x32_f16(Al[kk], Bh0, azl, 0, 0, 0);
            agl = __builtin_amdgcn_mfma_f32_16x16x32_f16(Al[kk], Bh1, agl, 0, 0, 0);
            ahl = __builtin_amdgcn_mfma_f32_16x16x32_f16(Al[kk], Bh2, ahl, 0, 0, 0);
            azl = __builtin_amdgcn_mfma_f32_16x16x32_f16(Ah[kk], Blo[0][kk].h, azl, 0, 0, 0);
            agl = __builtin_amdgcn_mfma_f32_16x16x32_f16(Ah[kk], Blo[1][kk].h, agl, 0, 0, 0);
            ahl = __builtin_amdgcn_mfma_f32_16x16x32_f16(Ah[kk], Blo[2][kk].h, ahl, 0, 0, 0);
        }

        __syncthreads();   // red(t-1) fully consumed by epilogue waves
#pragma unroll
        for (int r = 0; r < 4; ++r) {
            int idx = (q * 4 + r) * 16 + n;  // row(m)=quad*4+reg, col(n)=lane&15
            red[0][w][idx] = az[r] * S12 + azl[r] * S23;   // pow2 scales exact
            red[1][w][idx] = ag[r] * S12 + agl[r] * S23;
            red[2][w][idx] = ah[r] * S12 + ahl[r] * S23;
        }
        __syncthreads();   // red(t) ready

        if (tid < 256) {
            double rz = bz, rr = br_, rh = bh_;
#pragma unroll
            for (int ww = 0; ww < 8; ++ww) {
                rz += (double)red[0][ww][tid];
                rr += (double)red[1][ww][tid];
                rh += (double)red[2][ww][tid];
            }
            size_t bt = (size_t)bb * 128 + t;
            double z = 1.0 / (1.0 + exp(-((double)xz + rz)));
            double rg = 1.0 / (1.0 + exp(-((double)xr + rr)));
            double hh = tanh((double)xh + rg * rh);
            double hn = z * hp + (1.0 - z) * hh;
            hp = hn;
            float hnf = (float)hn;

            if (t < 127) {
                // publish h FIRST (scaled f16 split, packed pairs, coherent)
                u16 myhi, mylo;
                fsplit16d(hn, myhi, mylo);
                unsigned me = (unsigned)myhi | ((unsigned)mylo << 16);
                unsigned ot = __shfl_xor(me, 1);
                if ((tid & 1) == 0) {
                    unsigned hi32 = (me & 0xFFFFu) | ((ot & 0xFFFFu) << 16);
                    unsigned lo32 = (me >> 16) | (ot & 0xFFFF0000u);
                    __hip_atomic_store((unsigned*)(hhi_out + ho), hi32, __ATOMIC_RELAXED, __HIP_MEMORY_SCOPE_AGENT);
                    __hip_atomic_store((unsigned*)(hlo_out + ho), lo32, __ATOMIC_RELAXED, __HIP_MEMORY_SCOPE_AGENT);
                }
                // drain h stores only, then flag (out-store comes after)
                asm volatile("s_waitcnt vmcnt(0)" ::: "memory");
                if (lane == 0)
                    __hip_atomic_store(sf + ut * 4 + w, (unsigned)(t + 1),
                                       __ATOMIC_RELAXED, __HIP_MEMORY_SCOPE_AGENT);
            }

            __builtin_nontemporal_store(hnf, &out[bt * 1024 + u]);
            if (t == 127) __builtin_nontemporal_store(hnf, &out[8388608 + ho]);

            // prefetch next step's xin (latency hides under next poll/MFMA)
            if (t < 127) {
                size_t xo = (bt + 1) * 3072;
                xz = xin[xo + u];
                xr = xin[xo + 1024 + u];
                xh = xin[xo + 2048 + u];
            }
        }
    }
}

extern "C" void kernel_launch(void* const* d_in, const int* in_sizes, int n_in,
                              void* d_out, int out_size, void* d_ws, size_t ws_size,
                              hipStream_t stream) {
    const int* x = (const int*)d_in[0];
    const float* hid = (const float*)d_in[1];
    const float* E = (const float*)d_in[2];
    const float* W = (const float*)d_in[3];
    const float* U = (const float*)d_in[4];
    const float* b = (const float*)d_in[5];
    float* out = (float*)d_out;

    char* ws = (char*)d_ws;
    u16* hhi0 = (u16*)(ws + 0);                // 131072
    u16* hhi1 = (u16*)(ws + 131072);           // 131072
    u16* hlo0 = (u16*)(ws + 262144);           // 131072
    u16* hlo1 = (u16*)(ws + 393216);           // 131072
    u16* UThi = (u16*)(ws + 524288);           // 6291456
    u16* UTlo = (u16*)(ws + 6815744);          // 6291456
    u16* WThi = (u16*)(ws + 13107200);         // 1572864 (dead after xin_kernel)
    u16* WTlo = (u16*)(ws + 14680064);         // 1572864
    float* xin = (float*)(ws + 16777216);      // 100663296 -> total 117440512
    unsigned* bar = (unsigned*)(ws + 13107200);  // reuse dead WThi region (4KB)

    prep_h<<<256, 256, 0, stream>>>(hid, hhi0, hlo0);
    transpose_split<<<dim3(96, 32), 256, 0, stream>>>(U, UThi, UTlo, 1024, 3072);
    transpose_split<<<dim3(96, 8), 256, 0, stream>>>(W, WThi, WTlo, 256, 3072);
    xin_kernel<<<1536, 256, 0, stream>>>(x, E, WThi, WTlo, b, xin);
    init_barrier<<<4, 256, 0, stream>>>(bar);
    gru_persistent<<<256, 512, 0, stream>>>(UThi, UTlo, b + 3072, xin, hid,
                                            hhi0, hhi1, hlo0, hlo1, out, bar);
}

// Round 13
// 958.411 us; speedup vs baseline: 1.5602x; 1.5602x over previous
//
#include <hip/hip_runtime.h>
#include <math.h>

typedef unsigned short u16;
typedef _Float16 f16;
typedef f16 v8h __attribute__((ext_vector_type(8)));
typedef float v4f __attribute__((ext_vector_type(4)));
typedef unsigned v4u __attribute__((ext_vector_type(4)));

union Frag { v8h h; u16 s[8]; unsigned u[4]; v4u u4; };
union HU { f16 h; u16 u; };

// Scaled f16 pair split: v*64 ~= hi + lo * 2^-11, residual ~2^-22|v*64|.
__device__ __forceinline__ void fsplit16s(float v, u16& hi, u16& lo) {
    HU a, b;
    float vs = v * 64.f;                // exact (pow2 scale)
    a.h = (f16)vs;                      // RNE, rel err <= 2^-11
    float d = vs - (float)a.h;          // exact (Sterbenz)
    b.h = (f16)(d * 2048.f);            // rel err <= 2^-11 => total ~2^-22
    hi = a.u; lo = b.u;
}

// Same split, taken directly from a double (h publish path).
__device__ __forceinline__ void fsplit16d(double v, u16& hi, u16& lo) {
    HU a, b;
    double vs = v * 64.0;
    a.h = (f16)vs;                      // double->f16 RNE
    float d = (float)(vs - (double)a.h);
    b.h = (f16)(d * 2048.f);
    hi = a.u; lo = b.u;
}

__device__ __forceinline__ void split8s(const float* __restrict__ p, v8h& hi, v8h& lo) {
    Frag h, l;
#pragma unroll
    for (int j = 0; j < 8; ++j) {
        u16 a, b;
        fsplit16s(p[j], a, b);
        h.s[j] = a;
        l.s[j] = b;
    }
    hi = h.h; lo = l.h;
}

// Coherent (L1/L2-bypassing) 16B vector load; caller must s_waitcnt vmcnt(0).
__device__ __forceinline__ Frag load16_sc(const u16* p) {
    v4u r;
    asm volatile("global_load_dwordx4 %0, %1, off sc0 sc1" : "=v"(r) : "v"(p) : "memory");
    Frag f; f.u4 = r;
    return f;
}

// Cached 16B vector load at a pinned issue point; caller must s_waitcnt vmcnt(0).
__device__ __forceinline__ Frag load16_nc(const u16* p) {
    v4u r;
    asm volatile("global_load_dwordx4 %0, %1, off" : "=v"(r) : "v"(p) : "memory");
    Frag f; f.u4 = r;
    return f;
}

// ---------------------------------------------------------------------------
__global__ void prep_h(const float* __restrict__ hid, u16* __restrict__ hhi, u16* __restrict__ hlo) {
    int i = blockIdx.x * 256 + threadIdx.x;  // 65536
    u16 h, l;
    fsplit16s(hid[i], h, l);
    hhi[i] = h;
    hlo[i] = l;
}

// ---------------------------------------------------------------------------
// Transpose + scaled-f16-pair split (used for both U and W).
__global__ void transpose_split(const float* __restrict__ src, u16* __restrict__ dhi,
                                u16* __restrict__ dlo, int R, int C) {
    __shared__ float tile[32][33];
    int tid = threadIdx.x;
    int tx = tid & 31, ty = tid >> 5;
    int c0 = blockIdx.x * 32, r0 = blockIdx.y * 32;
#pragma unroll
    for (int i = 0; i < 4; ++i)
        tile[ty + i * 8][tx] = src[(size_t)(r0 + ty + i * 8) * C + c0 + tx];
    __syncthreads();
#pragma unroll
    for (int i = 0; i < 4; ++i) {
        int c = c0 + ty + i * 8;
        float v = tile[tx][ty + i * 8];
        size_t o = (size_t)c * R + r0 + tx;
        u16 h, l;
        fsplit16s(v, h, l);
        dhi[o] = h;
        dlo[o] = l;
    }
}

__global__ void init_barrier(unsigned* __restrict__ bar) {
    bar[blockIdx.x * 256 + threadIdx.x] = 0u;  // 1024 subflags: 4 groups x 64 blocks x 4 waves
}

// ---------------------------------------------------------------------------
// Persistent GRU v17 = v13 (flag dataflow, 956us, 4.9e-4, identity mapping)
// + xin FUSED into the step loop.  xt = E[x_t]@W + b0, K=256 split across
// the 8 waves (32 k each), accumulated pre-gate (h-independent -> fills the
// poll idle).  Gates z,r: xt folds into the same accumulators as U*h.
// Gate h: xt must stay SEPARATE (hh = tanh(xh + r*rec_h)), so it gets its
// own accumulator pair and a 4th red plane.  b0 folds into epilogue biases
// (z,r) or the xh sum (h).  Removes xin_kernel + 100MB plane + prefetch.
// ---------------------------------------------------------------------------
__global__ __launch_bounds__(512, 1) void gru_persistent(
        const u16* __restrict__ UThi, const u16* __restrict__ UTlo,
        const u16* __restrict__ WThi, const u16* __restrict__ WTlo,
        const float* __restrict__ b, const int* __restrict__ x,
        const float* __restrict__ E, const float* __restrict__ hid,
        u16* __restrict__ hhi0, u16* __restrict__ hhi1,
        u16* __restrict__ hlo0, u16* __restrict__ hlo1,
        float* __restrict__ out, unsigned* __restrict__ bar) {
    __shared__ u16 u_lds[3 * 128 * 17 * 8];   // 104448 B
    __shared__ float red[4][8][256];          // 32768 B (4th plane = xh)
    int tid = threadIdx.x;
    int w = tid >> 6, lane = tid & 63;
    int n = lane & 15, q = lane >> 4;
    int bg = blockIdx.x >> 6;          // 0..3  (v13 identity mapping)
    int ut = blockIdx.x & 63;          // 0..63
    int b0r = bg * 16;
    int u0 = ut * 16;
    unsigned* sf = bar + bg * 256;
    unsigned* poll_addr = sf + w * 32 + (lane & 31);

    for (int i = tid; i < 3 * 128 * 16; i += 512) {  // U-hi -> LDS (once)
        int g = i >> 11;
        int rem = i & 2047;
        int chunk = rem >> 4;
        int col = rem & 15;
        *(v4u*)(u_lds + (size_t)((g * 128 + chunk) * 17 + col) * 8) =
            *(const v4u*)(UThi + (size_t)(g * 1024 + u0 + col) * 1024 + chunk * 8);
    }
    __syncthreads();

    size_t aoff = (size_t)(b0r + n) * 1024 + w * 128 + q * 8;
    size_t uloff = (size_t)(u0 + n) * 1024 + w * 128 + q * 8;

    // W^T fragments (hi+lo), this wave's K-chunk [w*32+q*8, +8): 24 VGPR
    Frag Wh_r[3], Wl_r[3];
#pragma unroll
    for (int g = 0; g < 3; ++g) {
        size_t wo = (size_t)(g * 1024 + u0 + n) * 256 + w * 32 + q * 8;
        Wh_r[g].u4 = *(const v4u*)(WThi + wo);
        Wl_r[g].u4 = *(const v4u*)(WTlo + wo);
    }

    const int* xrow = x + (size_t)(b0r + n) * 128;  // token stream, row b0r+n

    // epilogue state (tid < 256)
    int bl = tid >> 4, ul = tid & 15;
    int bb = b0r + bl;
    int u = u0 + ul;
    size_t ho = (size_t)bb * 1024 + u;
    double bz = 0.0, br_ = 0.0, bxh = 0.0, brh = 0.0, hp = 0.0;
    if (tid < 256) {
        bz = (double)b[u0 + ul] + (double)b[3072 + u0 + ul];             // b0z+b1z
        br_ = (double)b[1024 + u0 + ul] + (double)b[3072 + 1024 + u0 + ul];
        bxh = (double)b[2048 + u0 + ul];                                  // b0h (input side)
        brh = (double)b[3072 + 2048 + u0 + ul];                           // b1h (recurrent side)
        hp = (double)hid[ho];
    }

    const float S12 = 2.44140625e-4f;           // 2^-12
    const float S23 = 1.1920928955078125e-7f;   // 2^-23

    for (int t = 0; t < 128; ++t) {
        const u16* hhi_in = (t & 1) ? hhi1 : hhi0;
        const u16* hlo_in = (t & 1) ? hlo1 : hlo0;
        u16* hhi_out = (t & 1) ? hhi0 : hhi1;
        u16* hlo_out = (t & 1) ? hlo0 : hlo1;

        // U-lo stream: issue before the gate so L2 latency hides under it.
        Frag Blo[3][4];
#pragma unroll
        for (int g = 0; g < 3; ++g)
#pragma unroll
            for (int kk = 0; kk < 4; ++kk)
                Blo[g][kk] = load16_nc(UTlo + uloff + (size_t)g * 1048576 + kk * 32);

        v4f az = {0.f, 0.f, 0.f, 0.f}, ag = az, ah = az;      // main (2^12)
        v4f azl = az, agl = az, ahl = az;                      // aux (2^23)
        v4f axh = az, axhl = az;                               // xt for gate h

        // --- Fused xt = E[x_t]@W: h-independent, fills the poll idle ---
        {
            int tok = xrow[t];
            const float* erow = E + (size_t)tok * 256 + w * 32 + q * 8;
            v8h EAh, EAl;
            split8s(erow, EAh, EAl);
            az  = __builtin_amdgcn_mfma_f32_16x16x32_f16(EAh, Wh_r[0].h, az, 0, 0, 0);
            ag  = __builtin_amdgcn_mfma_f32_16x16x32_f16(EAh, Wh_r[1].h, ag, 0, 0, 0);
            axh = __builtin_amdgcn_mfma_f32_16x16x32_f16(EAh, Wh_r[2].h, axh, 0, 0, 0);
            azl  = __builtin_amdgcn_mfma_f32_16x16x32_f16(EAl, Wh_r[0].h, azl, 0, 0, 0);
            agl  = __builtin_amdgcn_mfma_f32_16x16x32_f16(EAl, Wh_r[1].h, agl, 0, 0, 0);
            axhl = __builtin_amdgcn_mfma_f32_16x16x32_f16(EAl, Wh_r[2].h, axhl, 0, 0, 0);
            azl  = __builtin_amdgcn_mfma_f32_16x16x32_f16(EAh, Wl_r[0].h, azl, 0, 0, 0);
            agl  = __builtin_amdgcn_mfma_f32_16x16x32_f16(EAh, Wl_r[1].h, agl, 0, 0, 0);
            axhl = __builtin_amdgcn_mfma_f32_16x16x32_f16(EAh, Wl_r[2].h, axhl, 0, 0, 0);
        }

        // --- Dataflow gate: wait for THIS wave's 8 producers (32 subflags).
        if (t > 0) {
            unsigned target = (unsigned)t;
            while (true) {
                unsigned v = __hip_atomic_load(poll_addr, __ATOMIC_RELAXED, __HIP_MEMORY_SCOPE_AGENT);
                if (__all(v >= target)) break;
                __builtin_amdgcn_s_sleep(1);
            }
        }

        // --- A fragments: coherent dwordx4 loads, all issued, one drain ---
        v8h Ah[4], Al[4];
#pragma unroll
        for (int kk = 0; kk < 4; ++kk) {
            Ah[kk] = load16_sc(hhi_in + aoff + kk * 32).h;
            Al[kk] = load16_sc(hlo_in + aoff + kk * 32).h;
        }
        asm volatile("s_waitcnt vmcnt(0)" ::: "memory");

#pragma unroll
        for (int kk = 0; kk < 4; ++kk) {
            int chunk = w * 16 + kk * 4 + q;
            const u16* lp = u_lds + (size_t)(chunk * 17 + n) * 8;
            Frag f0, f1, f2;
            f0.u4 = *(const v4u*)(lp);
            f1.u4 = *(const v4u*)(lp + 128 * 17 * 8);
            f2.u4 = *(const v4u*)(lp + 2 * 128 * 17 * 8);
            v8h Bh0 = f0.h, Bh1 = f1.h, Bh2 = f2.h;
            az = __builtin_amdgcn_mfma_f32_16x16x32_f16(Ah[kk], Bh0, az, 0, 0, 0);
            ag = __builtin_amdgcn_mfma_f32_16x16x32_f16(Ah[kk], Bh1, ag, 0, 0, 0);
            ah = __builtin_amdgcn_mfma_f32_16x16x32_f16(Ah[kk], Bh2, ah, 0, 0, 0);
            azl = __builtin_amdgcn_mfma_f32_16x16x32_f16(Al[kk], Bh0, azl, 0, 0, 0);
            agl = __builtin_amdgcn_mfma_f32_16x16x32_f16(Al[kk], Bh1, agl, 0, 0, 0);
            ahl = __builtin_amdgcn_mfma_f32_16x16x32_f16(Al[kk], Bh2, ahl, 0, 0, 0);
            azl = __builtin_amdgcn_mfma_f32_16x16x32_f16(Ah[kk], Blo[0][kk].h, azl, 0, 0, 0);
            agl = __builtin_amdgcn_mfma_f32_16x16x32_f16(Ah[kk], Blo[1][kk].h, agl, 0, 0, 0);
            ahl = __builtin_amdgcn_mfma_f32_16x16x32_f16(Ah[kk], Blo[2][kk].h, ahl, 0, 0, 0);
        }

        __syncthreads();   // red(t-1) fully consumed by epilogue waves
#pragma unroll
        for (int r = 0; r < 4; ++r) {
            int idx = (q * 4 + r) * 16 + n;
            red[0][w][idx] = az[r] * S12 + azl[r] * S23;
            red[1][w][idx] = ag[r] * S12 + agl[r] * S23;
            red[2][w][idx] = ah[r] * S12 + ahl[r] * S23;   // recurrent-h only
            red[3][w][idx] = axh[r] * S12 + axhl[r] * S23; // input-h only
        }
        __syncthreads();   // red(t) ready

        if (tid < 256) {
            double rz = bz, rr = br_, rh = brh, xh = bxh;
#pragma unroll
            for (int ww = 0; ww < 8; ++ww) {
                rz += (double)red[0][ww][tid];
                rr += (double)red[1][ww][tid];
                rh += (double)red[2][ww][tid];
                xh += (double)red[3][ww][tid];
            }
            size_t bt = (size_t)bb * 128 + t;
            double z = 1.0 / (1.0 + exp(-rz));
            double rg = 1.0 / (1.0 + exp(-rr));
            double hh = tanh(xh + rg * rh);
            double hn = z * hp + (1.0 - z) * hh;
            hp = hn;
            float hnf = (float)hn;

            if (t < 127) {
                u16 myhi, mylo;
                fsplit16d(hn, myhi, mylo);
                unsigned me = (unsigned)myhi | ((unsigned)mylo << 16);
                unsigned ot = __shfl_xor(me, 1);
                if ((tid & 1) == 0) {
                    unsigned hi32 = (me & 0xFFFFu) | ((ot & 0xFFFFu) << 16);
                    unsigned lo32 = (me >> 16) | (ot & 0xFFFF0000u);
                    __hip_atomic_store((unsigned*)(hhi_out + ho), hi32, __ATOMIC_RELAXED, __HIP_MEMORY_SCOPE_AGENT);
                    __hip_atomic_store((unsigned*)(hlo_out + ho), lo32, __ATOMIC_RELAXED, __HIP_MEMORY_SCOPE_AGENT);
                }
                asm volatile("s_waitcnt vmcnt(0)" ::: "memory");
                if (lane == 0)
                    __hip_atomic_store(sf + ut * 4 + w, (unsigned)(t + 1),
                                       __ATOMIC_RELAXED, __HIP_MEMORY_SCOPE_AGENT);
            }

            __builtin_nontemporal_store(hnf, &out[bt * 1024 + u]);
            if (t == 127) __builtin_nontemporal_store(hnf, &out[8388608 + ho]);
        }
    }
}

extern "C" void kernel_launch(void* const* d_in, const int* in_sizes, int n_in,
                              void* d_out, int out_size, void* d_ws, size_t ws_size,
                              hipStream_t stream) {
    const int* x = (const int*)d_in[0];
    const float* hid = (const float*)d_in[1];
    const float* E = (const float*)d_in[2];
    const float* W = (const float*)d_in[3];
    const float* U = (const float*)d_in[4];
    const float* b = (const float*)d_in[5];
    float* out = (float*)d_out;

    char* ws = (char*)d_ws;
    u16* hhi0 = (u16*)(ws + 0);                // 131072
    u16* hhi1 = (u16*)(ws + 131072);           // 131072
    u16* hlo0 = (u16*)(ws + 262144);           // 131072
    u16* hlo1 = (u16*)(ws + 393216);           // 131072
    u16* UThi = (u16*)(ws + 524288);           // 6291456
    u16* UTlo = (u16*)(ws + 6815744);          // 6291456
    u16* WThi = (u16*)(ws + 13107200);         // 1572864 (LIVE during gru now)
    u16* WTlo = (u16*)(ws + 14680064);         // 1572864
    unsigned* bar = (unsigned*)(ws + 16252928);  // 4096 (own region, no alias)

    prep_h<<<256, 256, 0, stream>>>(hid, hhi0, hlo0);
    transpose_split<<<dim3(96, 32), 256, 0, stream>>>(U, UThi, UTlo, 1024, 3072);
    transpose_split<<<dim3(96, 8), 256, 0, stream>>>(W, WThi, WTlo, 256, 3072);
    init_barrier<<<4, 256, 0, stream>>>(bar);
    gru_persistent<<<256, 512, 0, stream>>>(UThi, UTlo, WThi, WTlo, b, x, E, hid,
                                            hhi0, hhi1, hlo0, hlo1, out, bar);
}

// Round 14
// 944.159 us; speedup vs baseline: 1.5837x; 1.0151x over previous
//
#include <hip/hip_runtime.h>
#include <math.h>

typedef unsigned short u16;
typedef _Float16 f16;
typedef f16 v8h __attribute__((ext_vector_type(8)));
typedef float v4f __attribute__((ext_vector_type(4)));
typedef unsigned v4u __attribute__((ext_vector_type(4)));

union Frag { v8h h; u16 s[8]; unsigned u[4]; v4u u4; };
union HU { f16 h; u16 u; };

// Scaled f16 pair split: v*64 ~= hi + lo * 2^-11, residual ~2^-22|v*64|.
__device__ __forceinline__ void fsplit16s(float v, u16& hi, u16& lo) {
    HU a, b;
    float vs = v * 64.f;                // exact (pow2 scale)
    a.h = (f16)vs;                      // RNE, rel err <= 2^-11
    float d = vs - (float)a.h;          // exact (Sterbenz)
    b.h = (f16)(d * 2048.f);            // rel err <= 2^-11 => total ~2^-22
    hi = a.u; lo = b.u;
}

// Same split, taken directly from a double (h publish path).
__device__ __forceinline__ void fsplit16d(double v, u16& hi, u16& lo) {
    HU a, b;
    double vs = v * 64.0;
    a.h = (f16)vs;                      // double->f16 RNE
    float d = (float)(vs - (double)a.h);
    b.h = (f16)(d * 2048.f);
    hi = a.u; lo = b.u;
}

__device__ __forceinline__ void split8s(const float* __restrict__ p, v8h& hi, v8h& lo) {
    Frag h, l;
#pragma unroll
    for (int j = 0; j < 8; ++j) {
        u16 a, b;
        fsplit16s(p[j], a, b);
        h.s[j] = a;
        l.s[j] = b;
    }
    hi = h.h; lo = l.h;
}

// Coherent (L1/L2-bypassing) 16B vector load; caller must s_waitcnt vmcnt(0).
__device__ __forceinline__ Frag load16_sc(const u16* p) {
    v4u r;
    asm volatile("global_load_dwordx4 %0, %1, off sc0 sc1" : "=v"(r) : "v"(p) : "memory");
    Frag f; f.u4 = r;
    return f;
}

// Cached 16B vector load at a pinned issue point; caller must s_waitcnt vmcnt(0).
__device__ __forceinline__ Frag load16_nc(const u16* p) {
    v4u r;
    asm volatile("global_load_dwordx4 %0, %1, off" : "=v"(r) : "v"(p) : "memory");
    Frag f; f.u4 = r;
    return f;
}

__global__ void init_barrier(unsigned* __restrict__ bar) {
    bar[blockIdx.x * 256 + threadIdx.x] = 0u;  // 1024 subflags: 4 groups x 64 blocks x 4 waves
}

// ---------------------------------------------------------------------------
// Persistent GRU v18 = v17 (fused xin, 907us GRU, absmax 4.9e-4) with the
// ENTIRE prologue folded into kernel startup (bit-identical values):
//  - U-slice: loaded straight from U (f32) + inline fsplit16s; hi -> LDS
//    (same layout), lo -> self-written global scratch (block-private rows,
//    read back non-coherently each step from L2).  The 4 groups write
//    identical bytes to shared scratch rows -- benign idempotent race; own
//    visibility via drain + syncthreads.
//  - W fragments: loaded straight from W (f32) + inline split.
//  - prep_h deleted: at t=0 the A-fragments come directly from hid (f32)
//    with in-register split; h-buffers only ever hold published state.
// Main step loop byte-identical to v17.
// ---------------------------------------------------------------------------
__global__ __launch_bounds__(512, 1) void gru_persistent(
        const float* __restrict__ U, const float* __restrict__ W,
        u16* __restrict__ UTlo,
        const float* __restrict__ b, const int* __restrict__ x,
        const float* __restrict__ E, const float* __restrict__ hid,
        u16* __restrict__ hhi0, u16* __restrict__ hhi1,
        u16* __restrict__ hlo0, u16* __restrict__ hlo1,
        float* __restrict__ out, unsigned* __restrict__ bar) {
    __shared__ u16 u_lds[3 * 128 * 17 * 8];   // 104448 B
    __shared__ float red[4][8][256];          // 32768 B (4th plane = xh)
    int tid = threadIdx.x;
    int w = tid >> 6, lane = tid & 63;
    int n = lane & 15, q = lane >> 4;
    int bg = blockIdx.x >> 6;          // 0..3  (identity mapping)
    int ut = blockIdx.x & 63;          // 0..63
    int b0r = bg * 16;
    int u0 = ut * 16;
    unsigned* sf = bar + bg * 256;
    unsigned* poll_addr = sf + w * 32 + (lane & 31);

    // --- Fused U transpose+split: U (f32) -> u_lds (hi) + UTlo scratch (lo)
    for (int i = tid; i < 3 * 128 * 16; i += 512) {
        int g = i >> 11;           // gate
        int rem = i & 2047;
        int chunk = rem >> 4;      // k-base = chunk*8
        int col = rem & 15;
        int gc = g * 1024 + u0 + col;
        Frag h_, l_;
#pragma unroll
        for (int j = 0; j < 8; ++j) {
            u16 a, bq;
            fsplit16s(U[(size_t)(chunk * 8 + j) * 3072 + gc], a, bq);
            h_.s[j] = a;
            l_.s[j] = bq;
        }
        *(v4u*)(u_lds + (size_t)((g * 128 + chunk) * 17 + col) * 8) = h_.u4;
        *(v4u*)(UTlo + (size_t)gc * 1024 + chunk * 8) = l_.u4;
    }
    asm volatile("s_waitcnt vmcnt(0)" ::: "memory");  // own UTlo stores -> L2
    __syncthreads();

    size_t aoff = (size_t)(b0r + n) * 1024 + w * 128 + q * 8;
    size_t uloff = (size_t)(u0 + n) * 1024 + w * 128 + q * 8;

    // --- Fused W transpose+split: this wave's K-chunk -> 24 VGPR frags
    Frag Wh_r[3], Wl_r[3];
#pragma unroll
    for (int g = 0; g < 3; ++g) {
        int gc = g * 1024 + u0 + n;
#pragma unroll
        for (int j = 0; j < 8; ++j) {
            u16 a, bq;
            fsplit16s(W[(size_t)(w * 32 + q * 8 + j) * 3072 + gc], a, bq);
            Wh_r[g].s[j] = a;
            Wl_r[g].s[j] = bq;
        }
    }

    const int* xrow = x + (size_t)(b0r + n) * 128;  // token stream, row b0r+n

    // epilogue state (tid < 256)
    int bl = tid >> 4, ul = tid & 15;
    int bb = b0r + bl;
    int u = u0 + ul;
    size_t ho = (size_t)bb * 1024 + u;
    double bz = 0.0, br_ = 0.0, bxh = 0.0, brh = 0.0, hp = 0.0;
    if (tid < 256) {
        bz = (double)b[u0 + ul] + (double)b[3072 + u0 + ul];             // b0z+b1z
        br_ = (double)b[1024 + u0 + ul] + (double)b[3072 + 1024 + u0 + ul];
        bxh = (double)b[2048 + u0 + ul];                                  // b0h (input side)
        brh = (double)b[3072 + 2048 + u0 + ul];                           // b1h (recurrent side)
        hp = (double)hid[ho];
    }

    const float S12 = 2.44140625e-4f;           // 2^-12
    const float S23 = 1.1920928955078125e-7f;   // 2^-23

    for (int t = 0; t < 128; ++t) {
        const u16* hhi_in = (t & 1) ? hhi1 : hhi0;
        const u16* hlo_in = (t & 1) ? hlo1 : hlo0;
        u16* hhi_out = (t & 1) ? hhi0 : hhi1;
        u16* hlo_out = (t & 1) ? hlo0 : hlo1;

        // U-lo stream: issue before the gate so L2 latency hides under it.
        Frag Blo[3][4];
#pragma unroll
        for (int g = 0; g < 3; ++g)
#pragma unroll
            for (int kk = 0; kk < 4; ++kk)
                Blo[g][kk] = load16_nc(UTlo + uloff + (size_t)g * 1048576 + kk * 32);

        v4f az = {0.f, 0.f, 0.f, 0.f}, ag = az, ah = az;      // main (2^12)
        v4f azl = az, agl = az, ahl = az;                      // aux (2^23)
        v4f axh = az, axhl = az;                               // xt for gate h

        // --- Fused xt = E[x_t]@W: h-independent, fills the poll idle ---
        {
            int tok = xrow[t];
            const float* erow = E + (size_t)tok * 256 + w * 32 + q * 8;
            v8h EAh, EAl;
            split8s(erow, EAh, EAl);
            az  = __builtin_amdgcn_mfma_f32_16x16x32_f16(EAh, Wh_r[0].h, az, 0, 0, 0);
            ag  = __builtin_amdgcn_mfma_f32_16x16x32_f16(EAh, Wh_r[1].h, ag, 0, 0, 0);
            axh = __builtin_amdgcn_mfma_f32_16x16x32_f16(EAh, Wh_r[2].h, axh, 0, 0, 0);
            azl  = __builtin_amdgcn_mfma_f32_16x16x32_f16(EAl, Wh_r[0].h, azl, 0, 0, 0);
            agl  = __builtin_amdgcn_mfma_f32_16x16x32_f16(EAl, Wh_r[1].h, agl, 0, 0, 0);
            axhl = __builtin_amdgcn_mfma_f32_16x16x32_f16(EAl, Wh_r[2].h, axhl, 0, 0, 0);
            azl  = __builtin_amdgcn_mfma_f32_16x16x32_f16(EAh, Wl_r[0].h, azl, 0, 0, 0);
            agl  = __builtin_amdgcn_mfma_f32_16x16x32_f16(EAh, Wl_r[1].h, agl, 0, 0, 0);
            axhl = __builtin_amdgcn_mfma_f32_16x16x32_f16(EAh, Wl_r[2].h, axhl, 0, 0, 0);
        }

        // --- A fragments ---
        v8h Ah[4], Al[4];
        if (t == 0) {
            // directly from hid (f32) with in-register split -- no staging
#pragma unroll
            for (int kk = 0; kk < 4; ++kk)
                split8s(hid + aoff + kk * 32, Ah[kk], Al[kk]);
        } else {
            // Dataflow gate: wait for THIS wave's 8 producers (32 subflags).
            unsigned target = (unsigned)t;
            while (true) {
                unsigned v = __hip_atomic_load(poll_addr, __ATOMIC_RELAXED, __HIP_MEMORY_SCOPE_AGENT);
                if (__all(v >= target)) break;
                __builtin_amdgcn_s_sleep(1);
            }
            // coherent dwordx4 loads, all issued, one drain
#pragma unroll
            for (int kk = 0; kk < 4; ++kk) {
                Ah[kk] = load16_sc(hhi_in + aoff + kk * 32).h;
                Al[kk] = load16_sc(hlo_in + aoff + kk * 32).h;
            }
            asm volatile("s_waitcnt vmcnt(0)" ::: "memory");
        }

#pragma unroll
        for (int kk = 0; kk < 4; ++kk) {
            int chunk = w * 16 + kk * 4 + q;
            const u16* lp = u_lds + (size_t)(chunk * 17 + n) * 8;
            Frag f0, f1, f2;
            f0.u4 = *(const v4u*)(lp);
            f1.u4 = *(const v4u*)(lp + 128 * 17 * 8);
            f2.u4 = *(const v4u*)(lp + 2 * 128 * 17 * 8);
            v8h Bh0 = f0.h, Bh1 = f1.h, Bh2 = f2.h;
            az = __builtin_amdgcn_mfma_f32_16x16x32_f16(Ah[kk], Bh0, az, 0, 0, 0);
            ag = __builtin_amdgcn_mfma_f32_16x16x32_f16(Ah[kk], Bh1, ag, 0, 0, 0);
            ah = __builtin_amdgcn_mfma_f32_16x16x32_f16(Ah[kk], Bh2, ah, 0, 0, 0);
            azl = __builtin_amdgcn_mfma_f32_16x16x32_f16(Al[kk], Bh0, azl, 0, 0, 0);
            agl = __builtin_amdgcn_mfma_f32_16x16x32_f16(Al[kk], Bh1, agl, 0, 0, 0);
            ahl = __builtin_amdgcn_mfma_f32_16x16x32_f16(Al[kk], Bh2, ahl, 0, 0, 0);
            azl = __builtin_amdgcn_mfma_f32_16x16x32_f16(Ah[kk], Blo[0][kk].h, azl, 0, 0, 0);
            agl = __builtin_amdgcn_mfma_f32_16x16x32_f16(Ah[kk], Blo[1][kk].h, agl, 0, 0, 0);
            ahl = __builtin_amdgcn_mfma_f32_16x16x32_f16(Ah[kk], Blo[2][kk].h, ahl, 0, 0, 0);
        }

        __syncthreads();   // red(t-1) fully consumed by epilogue waves
#pragma unroll
        for (int r = 0; r < 4; ++r) {
            int idx = (q * 4 + r) * 16 + n;
            red[0][w][idx] = az[r] * S12 + azl[r] * S23;
            red[1][w][idx] = ag[r] * S12 + agl[r] * S23;
            red[2][w][idx] = ah[r] * S12 + ahl[r] * S23;   // recurrent-h only
            red[3][w][idx] = axh[r] * S12 + axhl[r] * S23; // input-h only
        }
        __syncthreads();   // red(t) ready

        if (tid < 256) {
            double rz = bz, rr = br_, rh = brh, xh = bxh;
#pragma unroll
            for (int ww = 0; ww < 8; ++ww) {
                rz += (double)red[0][ww][tid];
                rr += (double)red[1][ww][tid];
                rh += (double)red[2][ww][tid];
                xh += (double)red[3][ww][tid];
            }
            size_t bt = (size_t)bb * 128 + t;
            double z = 1.0 / (1.0 + exp(-rz));
            double rg = 1.0 / (1.0 + exp(-rr));
            double hh = tanh(xh + rg * rh);
            double hn = z * hp + (1.0 - z) * hh;
            hp = hn;
            float hnf = (float)hn;

            if (t < 127) {
                u16 myhi, mylo;
                fsplit16d(hn, myhi, mylo);
                unsigned me = (unsigned)myhi | ((unsigned)mylo << 16);
                unsigned ot = __shfl_xor(me, 1);
                if ((tid & 1) == 0) {
                    unsigned hi32 = (me & 0xFFFFu) | ((ot & 0xFFFFu) << 16);
                    unsigned lo32 = (me >> 16) | (ot & 0xFFFF0000u);
                    __hip_atomic_store((unsigned*)(hhi_out + ho), hi32, __ATOMIC_RELAXED, __HIP_MEMORY_SCOPE_AGENT);
                    __hip_atomic_store((unsigned*)(hlo_out + ho), lo32, __ATOMIC_RELAXED, __HIP_MEMORY_SCOPE_AGENT);
                }
                asm volatile("s_waitcnt vmcnt(0)" ::: "memory");
                if (lane == 0)
                    __hip_atomic_store(sf + ut * 4 + w, (unsigned)(t + 1),
                                       __ATOMIC_RELAXED, __HIP_MEMORY_SCOPE_AGENT);
            }

            __builtin_nontemporal_store(hnf, &out[bt * 1024 + u]);
            if (t == 127) __builtin_nontemporal_store(hnf, &out[8388608 + ho]);
        }
    }
}

extern "C" void kernel_launch(void* const* d_in, const int* in_sizes, int n_in,
                              void* d_out, int out_size, void* d_ws, size_t ws_size,
                              hipStream_t stream) {
    const int* x = (const int*)d_in[0];
    const float* hid = (const float*)d_in[1];
    const float* E = (const float*)d_in[2];
    const float* W = (const float*)d_in[3];
    const float* U = (const float*)d_in[4];
    const float* b = (const float*)d_in[5];
    float* out = (float*)d_out;

    char* ws = (char*)d_ws;
    u16* hhi0 = (u16*)(ws + 0);                // 131072
    u16* hhi1 = (u16*)(ws + 131072);           // 131072
    u16* hlo0 = (u16*)(ws + 262144);           // 131072
    u16* hlo1 = (u16*)(ws + 393216);           // 131072
    u16* UTlo = (u16*)(ws + 524288);           // 6291456 (self-written scratch)
    unsigned* bar = (unsigned*)(ws + 6815744); // 4096

    init_barrier<<<4, 256, 0, stream>>>(bar);
    gru_persistent<<<256, 512, 0, stream>>>(U, W, UTlo, b, x, E, hid,
                                            hhi0, hhi1, hlo0, hlo1, out, bar);
}

// Round 15
// 939.819 us; speedup vs baseline: 1.5910x; 1.0046x over previous
//
#include <hip/hip_runtime.h>
#include <math.h>

typedef unsigned short u16;
typedef _Float16 f16;
typedef f16 v8h __attribute__((ext_vector_type(8)));
typedef float v4f __attribute__((ext_vector_type(4)));
typedef unsigned v4u __attribute__((ext_vector_type(4)));

union Frag { v8h h; u16 s[8]; unsigned u[4]; v4u u4; };
union HU { f16 h; u16 u; };

// Scaled f16 pair split: v*64 ~= hi + lo * 2^-11, residual ~2^-22|v*64|.
__device__ __forceinline__ void fsplit16s(float v, u16& hi, u16& lo) {
    HU a, b;
    float vs = v * 64.f;                // exact (pow2 scale)
    a.h = (f16)vs;                      // RNE, rel err <= 2^-11
    float d = vs - (float)a.h;          // exact (Sterbenz)
    b.h = (f16)(d * 2048.f);            // rel err <= 2^-11 => total ~2^-22
    hi = a.u; lo = b.u;
}

// Same split, taken directly from a double (h publish path).
__device__ __forceinline__ void fsplit16d(double v, u16& hi, u16& lo) {
    HU a, b;
    double vs = v * 64.0;
    a.h = (f16)vs;                      // double->f16 RNE
    float d = (float)(vs - (double)a.h);
    b.h = (f16)(d * 2048.f);
    hi = a.u; lo = b.u;
}

__device__ __forceinline__ void split8s(const float* __restrict__ p, v8h& hi, v8h& lo) {
    Frag h, l;
#pragma unroll
    for (int j = 0; j < 8; ++j) {
        u16 a, b;
        fsplit16s(p[j], a, b);
        h.s[j] = a;
        l.s[j] = b;
    }
    hi = h.h; lo = l.h;
}

// Coherent (L1/L2-bypassing) 16B vector load; caller must s_waitcnt vmcnt(0).
__device__ __forceinline__ Frag load16_sc(const u16* p) {
    v4u r;
    asm volatile("global_load_dwordx4 %0, %1, off sc0 sc1" : "=v"(r) : "v"(p) : "memory");
    Frag f; f.u4 = r;
    return f;
}

// Cached 16B vector load at a pinned issue point; caller must s_waitcnt vmcnt(0).
__device__ __forceinline__ Frag load16_nc(const u16* p) {
    v4u r;
    asm volatile("global_load_dwordx4 %0, %1, off" : "=v"(r) : "v"(p) : "memory");
    Frag f; f.u4 = r;
    return f;
}

// ---------------------------------------------------------------------------
// Persistent GRU v19 = v18 (fused everything, 915us dispatch, absmax 4.9e-4)
// unchanged; launcher swaps the init_barrier kernel for hipMemsetAsync --
// single kernel launch total.  Kernel source byte-identical to v18:
//  - U-slice: loaded from U (f32) + inline fsplit16s; hi -> LDS, lo -> self-
//    written global scratch (L2-resident, re-read non-coherently each step).
//  - W fragments: loaded from W (f32) + inline split (24 VGPR).
//  - t=0 A-fragments direct from hid (f32) with in-register split.
//  - xt = E[x_t]@W fused pre-gate (h-independent, fills poll idle); gate-h
//    xt kept separate (4th red plane) since hh = tanh(xh + r*rec_h).
//  - Flag-array dataflow gate (per-wave 8 producers), publish-first f64
//    epilogue, h as scaled-f16 pair via coherent stores.
// ---------------------------------------------------------------------------
__global__ __launch_bounds__(512, 1) void gru_persistent(
        const float* __restrict__ U, const float* __restrict__ W,
        u16* __restrict__ UTlo,
        const float* __restrict__ b, const int* __restrict__ x,
        const float* __restrict__ E, const float* __restrict__ hid,
        u16* __restrict__ hhi0, u16* __restrict__ hhi1,
        u16* __restrict__ hlo0, u16* __restrict__ hlo1,
        float* __restrict__ out, unsigned* __restrict__ bar) {
    __shared__ u16 u_lds[3 * 128 * 17 * 8];   // 104448 B
    __shared__ float red[4][8][256];          // 32768 B (4th plane = xh)
    int tid = threadIdx.x;
    int w = tid >> 6, lane = tid & 63;
    int n = lane & 15, q = lane >> 4;
    int bg = blockIdx.x >> 6;          // 0..3  (identity mapping)
    int ut = blockIdx.x & 63;          // 0..63
    int b0r = bg * 16;
    int u0 = ut * 16;
    unsigned* sf = bar + bg * 256;
    unsigned* poll_addr = sf + w * 32 + (lane & 31);

    // --- Fused U transpose+split: U (f32) -> u_lds (hi) + UTlo scratch (lo)
    for (int i = tid; i < 3 * 128 * 16; i += 512) {
        int g = i >> 11;           // gate
        int rem = i & 2047;
        int chunk = rem >> 4;      // k-base = chunk*8
        int col = rem & 15;
        int gc = g * 1024 + u0 + col;
        Frag h_, l_;
#pragma unroll
        for (int j = 0; j < 8; ++j) {
            u16 a, bq;
            fsplit16s(U[(size_t)(chunk * 8 + j) * 3072 + gc], a, bq);
            h_.s[j] = a;
            l_.s[j] = bq;
        }
        *(v4u*)(u_lds + (size_t)((g * 128 + chunk) * 17 + col) * 8) = h_.u4;
        *(v4u*)(UTlo + (size_t)gc * 1024 + chunk * 8) = l_.u4;
    }
    asm volatile("s_waitcnt vmcnt(0)" ::: "memory");  // own UTlo stores -> L2
    __syncthreads();

    size_t aoff = (size_t)(b0r + n) * 1024 + w * 128 + q * 8;
    size_t uloff = (size_t)(u0 + n) * 1024 + w * 128 + q * 8;

    // --- Fused W transpose+split: this wave's K-chunk -> 24 VGPR frags
    Frag Wh_r[3], Wl_r[3];
#pragma unroll
    for (int g = 0; g < 3; ++g) {
        int gc = g * 1024 + u0 + n;
#pragma unroll
        for (int j = 0; j < 8; ++j) {
            u16 a, bq;
            fsplit16s(W[(size_t)(w * 32 + q * 8 + j) * 3072 + gc], a, bq);
            Wh_r[g].s[j] = a;
            Wl_r[g].s[j] = bq;
        }
    }

    const int* xrow = x + (size_t)(b0r + n) * 128;  // token stream, row b0r+n

    // epilogue state (tid < 256)
    int bl = tid >> 4, ul = tid & 15;
    int bb = b0r + bl;
    int u = u0 + ul;
    size_t ho = (size_t)bb * 1024 + u;
    double bz = 0.0, br_ = 0.0, bxh = 0.0, brh = 0.0, hp = 0.0;
    if (tid < 256) {
        bz = (double)b[u0 + ul] + (double)b[3072 + u0 + ul];             // b0z+b1z
        br_ = (double)b[1024 + u0 + ul] + (double)b[3072 + 1024 + u0 + ul];
        bxh = (double)b[2048 + u0 + ul];                                  // b0h (input side)
        brh = (double)b[3072 + 2048 + u0 + ul];                           // b1h (recurrent side)
        hp = (double)hid[ho];
    }

    const float S12 = 2.44140625e-4f;           // 2^-12
    const float S23 = 1.1920928955078125e-7f;   // 2^-23

    for (int t = 0; t < 128; ++t) {
        const u16* hhi_in = (t & 1) ? hhi1 : hhi0;
        const u16* hlo_in = (t & 1) ? hlo1 : hlo0;
        u16* hhi_out = (t & 1) ? hhi0 : hhi1;
        u16* hlo_out = (t & 1) ? hlo0 : hlo1;

        // U-lo stream: issue before the gate so L2 latency hides under it.
        Frag Blo[3][4];
#pragma unroll
        for (int g = 0; g < 3; ++g)
#pragma unroll
            for (int kk = 0; kk < 4; ++kk)
                Blo[g][kk] = load16_nc(UTlo + uloff + (size_t)g * 1048576 + kk * 32);

        v4f az = {0.f, 0.f, 0.f, 0.f}, ag = az, ah = az;      // main (2^12)
        v4f azl = az, agl = az, ahl = az;                      // aux (2^23)
        v4f axh = az, axhl = az;                               // xt for gate h

        // --- Fused xt = E[x_t]@W: h-independent, fills the poll idle ---
        {
            int tok = xrow[t];
            const float* erow = E + (size_t)tok * 256 + w * 32 + q * 8;
            v8h EAh, EAl;
            split8s(erow, EAh, EAl);
            az  = __builtin_amdgcn_mfma_f32_16x16x32_f16(EAh, Wh_r[0].h, az, 0, 0, 0);
            ag  = __builtin_amdgcn_mfma_f32_16x16x32_f16(EAh, Wh_r[1].h, ag, 0, 0, 0);
            axh = __builtin_amdgcn_mfma_f32_16x16x32_f16(EAh, Wh_r[2].h, axh, 0, 0, 0);
            azl  = __builtin_amdgcn_mfma_f32_16x16x32_f16(EAl, Wh_r[0].h, azl, 0, 0, 0);
            agl  = __builtin_amdgcn_mfma_f32_16x16x32_f16(EAl, Wh_r[1].h, agl, 0, 0, 0);
            axhl = __builtin_amdgcn_mfma_f32_16x16x32_f16(EAl, Wh_r[2].h, axhl, 0, 0, 0);
            azl  = __builtin_amdgcn_mfma_f32_16x16x32_f16(EAh, Wl_r[0].h, azl, 0, 0, 0);
            agl  = __builtin_amdgcn_mfma_f32_16x16x32_f16(EAh, Wl_r[1].h, agl, 0, 0, 0);
            axhl = __builtin_amdgcn_mfma_f32_16x16x32_f16(EAh, Wl_r[2].h, axhl, 0, 0, 0);
        }

        // --- A fragments ---
        v8h Ah[4], Al[4];
        if (t == 0) {
            // directly from hid (f32) with in-register split -- no staging
#pragma unroll
            for (int kk = 0; kk < 4; ++kk)
                split8s(hid + aoff + kk * 32, Ah[kk], Al[kk]);
        } else {
            // Dataflow gate: wait for THIS wave's 8 producers (32 subflags).
            unsigned target = (unsigned)t;
            while (true) {
                unsigned v = __hip_atomic_load(poll_addr, __ATOMIC_RELAXED, __HIP_MEMORY_SCOPE_AGENT);
                if (__all(v >= target)) break;
                __builtin_amdgcn_s_sleep(1);
            }
            // coherent dwordx4 loads, all issued, one drain
#pragma unroll
            for (int kk = 0; kk < 4; ++kk) {
                Ah[kk] = load16_sc(hhi_in + aoff + kk * 32).h;
                Al[kk] = load16_sc(hlo_in + aoff + kk * 32).h;
            }
            asm volatile("s_waitcnt vmcnt(0)" ::: "memory");
        }

#pragma unroll
        for (int kk = 0; kk < 4; ++kk) {
            int chunk = w * 16 + kk * 4 + q;
            const u16* lp = u_lds + (size_t)(chunk * 17 + n) * 8;
            Frag f0, f1, f2;
            f0.u4 = *(const v4u*)(lp);
            f1.u4 = *(const v4u*)(lp + 128 * 17 * 8);
            f2.u4 = *(const v4u*)(lp + 2 * 128 * 17 * 8);
            v8h Bh0 = f0.h, Bh1 = f1.h, Bh2 = f2.h;
            az = __builtin_amdgcn_mfma_f32_16x16x32_f16(Ah[kk], Bh0, az, 0, 0, 0);
            ag = __builtin_amdgcn_mfma_f32_16x16x32_f16(Ah[kk], Bh1, ag, 0, 0, 0);
            ah = __builtin_amdgcn_mfma_f32_16x16x32_f16(Ah[kk], Bh2, ah, 0, 0, 0);
            azl = __builtin_amdgcn_mfma_f32_16x16x32_f16(Al[kk], Bh0, azl, 0, 0, 0);
            agl = __builtin_amdgcn_mfma_f32_16x16x32_f16(Al[kk], Bh1, agl, 0, 0, 0);
            ahl = __builtin_amdgcn_mfma_f32_16x16x32_f16(Al[kk], Bh2, ahl, 0, 0, 0);
            azl = __builtin_amdgcn_mfma_f32_16x16x32_f16(Ah[kk], Blo[0][kk].h, azl, 0, 0, 0);
            agl = __builtin_amdgcn_mfma_f32_16x16x32_f16(Ah[kk], Blo[1][kk].h, agl, 0, 0, 0);
            ahl = __builtin_amdgcn_mfma_f32_16x16x32_f16(Ah[kk], Blo[2][kk].h, ahl, 0, 0, 0);
        }

        __syncthreads();   // red(t-1) fully consumed by epilogue waves
#pragma unroll
        for (int r = 0; r < 4; ++r) {
            int idx = (q * 4 + r) * 16 + n;
            red[0][w][idx] = az[r] * S12 + azl[r] * S23;
            red[1][w][idx] = ag[r] * S12 + agl[r] * S23;
            red[2][w][idx] = ah[r] * S12 + ahl[r] * S23;   // recurrent-h only
            red[3][w][idx] = axh[r] * S12 + axhl[r] * S23; // input-h only
        }
        __syncthreads();   // red(t) ready

        if (tid < 256) {
            double rz = bz, rr = br_, rh = brh, xh = bxh;
#pragma unroll
            for (int ww = 0; ww < 8; ++ww) {
                rz += (double)red[0][ww][tid];
                rr += (double)red[1][ww][tid];
                rh += (double)red[2][ww][tid];
                xh += (double)red[3][ww][tid];
            }
            size_t bt = (size_t)bb * 128 + t;
            double z = 1.0 / (1.0 + exp(-rz));
            double rg = 1.0 / (1.0 + exp(-rr));
            double hh = tanh(xh + rg * rh);
            double hn = z * hp + (1.0 - z) * hh;
            hp = hn;
            float hnf = (float)hn;

            if (t < 127) {
                u16 myhi, mylo;
                fsplit16d(hn, myhi, mylo);
                unsigned me = (unsigned)myhi | ((unsigned)mylo << 16);
                unsigned ot = __shfl_xor(me, 1);
                if ((tid & 1) == 0) {
                    unsigned hi32 = (me & 0xFFFFu) | ((ot & 0xFFFFu) << 16);
                    unsigned lo32 = (me >> 16) | (ot & 0xFFFF0000u);
                    __hip_atomic_store((unsigned*)(hhi_out + ho), hi32, __ATOMIC_RELAXED, __HIP_MEMORY_SCOPE_AGENT);
                    __hip_atomic_store((unsigned*)(hlo_out + ho), lo32, __ATOMIC_RELAXED, __HIP_MEMORY_SCOPE_AGENT);
                }
                asm volatile("s_waitcnt vmcnt(0)" ::: "memory");
                if (lane == 0)
                    __hip_atomic_store(sf + ut * 4 + w, (unsigned)(t + 1),
                                       __ATOMIC_RELAXED, __HIP_MEMORY_SCOPE_AGENT);
            }

            __builtin_nontemporal_store(hnf, &out[bt * 1024 + u]);
            if (t == 127) __builtin_nontemporal_store(hnf, &out[8388608 + ho]);
        }
    }
}

extern "C" void kernel_launch(void* const* d_in, const int* in_sizes, int n_in,
                              void* d_out, int out_size, void* d_ws, size_t ws_size,
                              hipStream_t stream) {
    const int* x = (const int*)d_in[0];
    const float* hid = (const float*)d_in[1];
    const float* E = (const float*)d_in[2];
    const float* W = (const float*)d_in[3];
    const float* U = (const float*)d_in[4];
    const float* b = (const float*)d_in[5];
    float* out = (float*)d_out;

    char* ws = (char*)d_ws;
    u16* hhi0 = (u16*)(ws + 0);                // 131072
    u16* hhi1 = (u16*)(ws + 131072);           // 131072
    u16* hlo0 = (u16*)(ws + 262144);           // 131072
    u16* hlo1 = (u16*)(ws + 393216);           // 131072
    u16* UTlo = (u16*)(ws + 524288);           // 6291456 (self-written scratch)
    unsigned* bar = (unsigned*)(ws + 6815744); // 4096

    // Barrier init via async memset (graph-capture-safe) -- no extra kernel.
    hipMemsetAsync(bar, 0, 4096, stream);
    gru_persistent<<<256, 512, 0, stream>>>(U, W, UTlo, b, x, E, hid,
                                            hhi0, hhi1, hlo0, hlo1, out, bar);
}